// Round 5
// baseline (459.528 us; speedup 1.0000x reference)
//
#include <hip/hip_runtime.h>
#include <stdint.h>

// Problem constants (Gemma3 attention block)
#define T_TOK 4096
#define DM    2560
#define NQ    8
#define NKV   4
#define HD    256
#define WIN   1024

using bf16x8 = __attribute__((ext_vector_type(8))) short;
using f32x4  = __attribute__((ext_vector_type(4))) float;
typedef unsigned short u16;

__device__ __forceinline__ u16 f2bf(float x) {
  union { float f; uint32_t u; } v; v.f = x;
  uint32_t u = v.u;
  return (u16)((u + 0x7fffu + ((u >> 16) & 1u)) >> 16);  // RNE
}
__device__ __forceinline__ float bf2f(u16 b) {
  union { uint32_t u; float f; } v; v.u = ((uint32_t)b) << 16;
  return v.f;
}

// async global->LDS, 16B per lane. LDS dest is wave-uniform base; HW adds lane*16.
__device__ __forceinline__ void async_cp16(const void* g, void* lds) {
  __builtin_amdgcn_global_load_lds(
      (const __attribute__((address_space(1))) uint32_t*)(uintptr_t)g,
      (__attribute__((address_space(3))) uint32_t*)(uint32_t)(uintptr_t)lds,
      16, 0, 0);
}

// ---------------------------------------------------------------------------
// f32 -> bf16 elementwise convert (vectorized float4 loads)
__global__ __launch_bounds__(256) void convert_f32_bf16(
    const float* __restrict__ in, u16* __restrict__ out, int n)
{
  for (int i = (blockIdx.x * 256 + threadIdx.x) * 4; i < n; i += gridDim.x * 256 * 4) {
    float4 v = *(const float4*)(in + i);
    ushort4 o;
    o.x = f2bf(v.x); o.y = f2bf(v.y); o.z = f2bf(v.z); o.w = f2bf(v.w);
    *(ushort4*)(out + i) = o;
  }
}

// ---------------------------------------------------------------------------
// Tiled transpose + convert: in f32 (R x C) row-major -> out bf16 (C x R)
__global__ __launch_bounds__(256) void transpose_f32_bf16(
    const float* __restrict__ in, u16* __restrict__ out, int R, int C)
{
  __shared__ u16 tile[64][65];
  const int r0 = blockIdx.y * 64, c0 = blockIdx.x * 64;
  const int tr = threadIdx.x >> 6, tc = threadIdx.x & 63;
  #pragma unroll
  for (int i = 0; i < 16; ++i) {
    int r = tr + i * 4;
    tile[r][tc] = f2bf(in[(size_t)(r0 + r) * C + c0 + tc]);
  }
  __syncthreads();
  #pragma unroll
  for (int i = 0; i < 16; ++i) {
    int c = tr + i * 4;
    out[(size_t)(c0 + c) * R + r0 + tc] = tile[tc][c];
  }
}

// ---------------------------------------------------------------------------
// bf16 GEMM: C(MxN) = A(MxK,row-major,lda) * B^T where B is (N x K,row-major,ldb).
// 128x128 tile, BK=64, 4 waves (2x2), global_load_lds staging, 16x16x32 MFMA.
// bf16 C store.
__global__ __launch_bounds__(256, 2) void gemm_bf16(
    const u16* __restrict__ A, const u16* __restrict__ B, u16* __restrict__ C,
    int Kd, int lda, int ldb, int ldc)
{
  __shared__ u16 As[128 * 64];
  __shared__ u16 Bs[128 * 64];
  const int tid = threadIdx.x;
  const int wave = tid >> 6, lane = tid & 63;
  const int lg = lane >> 4, lc = lane & 15;
  const int wr = wave >> 1, wc = wave & 1;
  const int m0 = blockIdx.y * 128, n0 = blockIdx.x * 128;

  const u16* Ab = A + (size_t)(m0 + (tid >> 3)) * lda + (tid & 7) * 8;
  const u16* Bb = B + (size_t)(n0 + (tid >> 3)) * ldb + (tid & 7) * 8;
  char* lAs = (char*)As + wave * 1024;
  char* lBs = (char*)Bs + wave * 1024;

  const f32x4 zf = {0.f, 0.f, 0.f, 0.f};
  f32x4 acc[4][4];
  #pragma unroll
  for (int i = 0; i < 4; ++i)
    #pragma unroll
    for (int j = 0; j < 4; ++j) acc[i][j] = zf;

  for (int kt = 0; kt < Kd; kt += 64) {
    #pragma unroll
    for (int is = 0; is < 4; ++is)
      async_cp16(Ab + (size_t)(is * 32) * lda + kt, lAs + is * 4096);
    #pragma unroll
    for (int is = 0; is < 4; ++is)
      async_cp16(Bb + (size_t)(is * 32) * ldb + kt, lBs + is * 4096);
    __syncthreads();
    #pragma unroll
    for (int kk = 0; kk < 2; ++kk) {
      bf16x8 af[4], bfr[4];
      #pragma unroll
      for (int i = 0; i < 4; ++i)
        af[i] = *(const bf16x8*)&As[(wr * 64 + i * 16 + lc) * 64 + kk * 32 + lg * 8];
      #pragma unroll
      for (int j = 0; j < 4; ++j)
        bfr[j] = *(const bf16x8*)&Bs[(wc * 64 + j * 16 + lc) * 64 + kk * 32 + lg * 8];
      #pragma unroll
      for (int i = 0; i < 4; ++i)
        #pragma unroll
        for (int j = 0; j < 4; ++j)
          acc[i][j] = __builtin_amdgcn_mfma_f32_16x16x32_bf16(af[i], bfr[j], acc[i][j], 0, 0, 0);
    }
    __syncthreads();
  }

  #pragma unroll
  for (int i = 0; i < 4; ++i)
    #pragma unroll
    for (int j = 0; j < 4; ++j)
      #pragma unroll
      for (int r = 0; r < 4; ++r) {
        int row = m0 + wr * 64 + i * 16 + lg * 4 + r;
        int col = n0 + wc * 64 + j * 16 + lc;
        C[(size_t)row * ldc + col] = f2bf(acc[i][j][r]);
      }
}

// Same GEMM, f32 C store (for the final o projection into d_out).
__global__ __launch_bounds__(256, 2) void gemm_bf16_f32out(
    const u16* __restrict__ A, const u16* __restrict__ B, float* __restrict__ C,
    int Kd, int lda, int ldb, int ldc)
{
  __shared__ u16 As[128 * 64];
  __shared__ u16 Bs[128 * 64];
  const int tid = threadIdx.x;
  const int wave = tid >> 6, lane = tid & 63;
  const int lg = lane >> 4, lc = lane & 15;
  const int wr = wave >> 1, wc = wave & 1;
  const int m0 = blockIdx.y * 128, n0 = blockIdx.x * 128;

  const u16* Ab = A + (size_t)(m0 + (tid >> 3)) * lda + (tid & 7) * 8;
  const u16* Bb = B + (size_t)(n0 + (tid >> 3)) * ldb + (tid & 7) * 8;
  char* lAs = (char*)As + wave * 1024;
  char* lBs = (char*)Bs + wave * 1024;

  const f32x4 zf = {0.f, 0.f, 0.f, 0.f};
  f32x4 acc[4][4];
  #pragma unroll
  for (int i = 0; i < 4; ++i)
    #pragma unroll
    for (int j = 0; j < 4; ++j) acc[i][j] = zf;

  for (int kt = 0; kt < Kd; kt += 64) {
    #pragma unroll
    for (int is = 0; is < 4; ++is)
      async_cp16(Ab + (size_t)(is * 32) * lda + kt, lAs + is * 4096);
    #pragma unroll
    for (int is = 0; is < 4; ++is)
      async_cp16(Bb + (size_t)(is * 32) * ldb + kt, lBs + is * 4096);
    __syncthreads();
    #pragma unroll
    for (int kk = 0; kk < 2; ++kk) {
      bf16x8 af[4], bfr[4];
      #pragma unroll
      for (int i = 0; i < 4; ++i)
        af[i] = *(const bf16x8*)&As[(wr * 64 + i * 16 + lc) * 64 + kk * 32 + lg * 8];
      #pragma unroll
      for (int j = 0; j < 4; ++j)
        bfr[j] = *(const bf16x8*)&Bs[(wc * 64 + j * 16 + lc) * 64 + kk * 32 + lg * 8];
      #pragma unroll
      for (int i = 0; i < 4; ++i)
        #pragma unroll
        for (int j = 0; j < 4; ++j)
          acc[i][j] = __builtin_amdgcn_mfma_f32_16x16x32_bf16(af[i], bfr[j], acc[i][j], 0, 0, 0);
    }
    __syncthreads();
  }

  #pragma unroll
  for (int i = 0; i < 4; ++i)
    #pragma unroll
    for (int j = 0; j < 4; ++j)
      #pragma unroll
      for (int r = 0; r < 4; ++r) {
        int row = m0 + wr * 64 + i * 16 + lg * 4 + r;
        int col = n0 + wc * 64 + j * 16 + lc;
        C[(size_t)row * ldc + col] = acc[i][j][r];
      }
}

// ---------------------------------------------------------------------------
// Fused RMSNorm + query-scale + RoPE. Reads qkv (T x 4096 bf16):
// cols [0,2048) = q (n-major), [2048,3072) = k, [3072,4096) = v.
// Writes: q -> qb (bf16), k -> kvout[0] (f32) + kb (bf16),
//         v -> kvout[1] (f32) + vb (bf16).
__global__ __launch_bounds__(256) void fuse_norm_rope(
    const u16* __restrict__ qkv, const float* __restrict__ qnw, const float* __restrict__ knw,
    const int* __restrict__ pos, u16* __restrict__ qb, u16* __restrict__ kb,
    u16* __restrict__ vb, float* __restrict__ kvout)
{
  const int t = blockIdx.x;
  const int wave = threadIdx.x >> 6, lane = threadIdx.x & 63;
  const float p = (float)pos[t];
  const float kf = 0.10381025296523007f;  // log2(10000)/128
  float s0, c0, s1, c1;
  sincosf(p * exp2f(-(float)lane * kf), &s0, &c0);
  sincosf(p * exp2f(-(float)(lane + 64) * kf), &s1, &c1);
  const u16* row = qkv + (size_t)t * 4096;

  for (int pp = 0; pp < 4; ++pp) {
    const int hr = pp * 4 + wave;  // 0..7 q, 8..11 k, 12..15 v
    if (hr >= 12) {
      const int kk = hr - 12;
      const u16* src = row + 3072 + kk * 256;
      float* dstf = kvout + (size_t)T_TOK * NKV * HD + ((size_t)t * NKV + kk) * HD;
      u16*   dstb = vb + ((size_t)t * NKV + kk) * HD;
      #pragma unroll
      for (int q4 = 0; q4 < 4; ++q4) {
        const u16 s = src[lane + q4 * 64];
        dstf[lane + q4 * 64] = bf2f(s);
        dstb[lane + q4 * 64] = s;
      }
    } else {
      const bool isq = hr < 8;
      const int cb = isq ? hr * 256 : 2048 + (hr - 8) * 256;
      float v0 = bf2f(row[cb + lane]);
      float v1 = bf2f(row[cb + lane + 64]);
      float v2 = bf2f(row[cb + lane + 128]);
      float v3 = bf2f(row[cb + lane + 192]);
      float ss = v0 * v0 + v1 * v1 + v2 * v2 + v3 * v3;
      #pragma unroll
      for (int off = 1; off < 64; off <<= 1) ss += __shfl_xor(ss, off);
      float sc = rsqrtf(ss * (1.0f / 256.0f) + 1e-6f);
      if (isq) sc *= 0.0625f;  // QUERY_PRE_ATTN_SCALAR^-0.5
      const float* wn = isq ? qnw : knw;
      v0 *= sc * wn[lane];
      v1 *= sc * wn[lane + 64];
      v2 *= sc * wn[lane + 128];
      v3 *= sc * wn[lane + 192];
      const float n0 = v0 * c0 - v2 * s0;
      const float n2 = v2 * c0 + v0 * s0;
      const float n1 = v1 * c1 - v3 * s1;
      const float n3 = v3 * c1 + v1 * s1;
      if (isq) {
        u16* dst = qb + (size_t)t * 2048 + hr * 256;
        dst[lane]       = f2bf(n0);
        dst[lane + 64]  = f2bf(n1);
        dst[lane + 128] = f2bf(n2);
        dst[lane + 192] = f2bf(n3);
      } else {
        const int kk = hr - 8;
        float* dstf = kvout + ((size_t)t * NKV + kk) * HD;
        dstf[lane]       = n0;
        dstf[lane + 64]  = n1;
        dstf[lane + 128] = n2;
        dstf[lane + 192] = n3;
        u16* dstb = kb + ((size_t)t * NKV + kk) * HD;
        dstb[lane]       = f2bf(n0);
        dstb[lane + 64]  = f2bf(n1);
        dstb[lane + 128] = f2bf(n2);
        dstb[lane + 192] = f2bf(n3);
      }
    }
  }
}

// ---------------------------------------------------------------------------
// Per-head V transpose: vb (T x NKV x HD bf16) -> vt (NKV x HD x T bf16)
__global__ __launch_bounds__(256) void transpose_v(
    const u16* __restrict__ vc, u16* __restrict__ vt)
{
  __shared__ u16 tile[64][65];
  const int kk = blockIdx.z;
  const int t0 = blockIdx.y * 64, h0 = blockIdx.x * 64;
  const int tr = threadIdx.x >> 6, tc = threadIdx.x & 63;
  #pragma unroll
  for (int i = 0; i < 16; ++i) {
    int tt = tr + i * 4;
    tile[tt][tc] = vc[((size_t)(t0 + tt) * NKV + kk) * HD + h0 + tc];
  }
  __syncthreads();
  #pragma unroll
  for (int i = 0; i < 16; ++i) {
    int h = tr + i * 4;
    vt[(size_t)kk * HD * T_TOK + (size_t)(h0 + h) * T_TOK + t0 + tc] = tile[tc][h];
  }
}

// ---------------------------------------------------------------------------
// Flash attention, sliding window 1024, GQA. Register-staged LDS tiles.
__global__ __launch_bounds__(256, 1) void attn_kernel(
    const u16* __restrict__ qb, const u16* __restrict__ kc,
    const u16* __restrict__ vt, u16* __restrict__ ob)
{
  __shared__ __align__(16) u16 Qs[64 * 256];
  __shared__ __align__(16) u16 Ks[64 * 256];
  __shared__ __align__(16) u16 Vts[256 * 64];
  __shared__ __align__(16) u16 Ps[64 * 64];
  __shared__ float m_part[4][64];
  __shared__ float s_part[4][64];
  __shared__ float m_arr[64], l_arr[64], a_arr[64];

  const int n = blockIdx.y;       // q head
  const int kk = n >> 1;          // kv head
  const int t0 = blockIdx.x * 64;
  const int tid = threadIdx.x;
  const int wave = tid >> 6, lane = tid & 63;
  const int lg = lane >> 4, lc = lane & 15;

  // stage Q block (64 x 256) once: reg-staged
  {
    const u16* qp = qb + (size_t)(t0 + (tid >> 5)) * 2048 + n * 256 + (tid & 31) * 8;
    u16* qd = Qs + (tid >> 5) * 256 + (tid & 31) * 8;
    bf16x8 tq[8];
    #pragma unroll
    for (int is = 0; is < 8; ++is) tq[is] = *(const bf16x8*)(qp + (size_t)is * 8 * 2048);
    #pragma unroll
    for (int is = 0; is < 8; ++is) *(bf16x8*)(qd + is * 8 * 256) = tq[is];
  }
  if (tid < 64) { m_arr[tid] = -1e30f; l_arr[tid] = 0.f; }

  const f32x4 zf = {0.f, 0.f, 0.f, 0.f};
  f32x4 o_acc[4][4];
  #pragma unroll
  for (int i = 0; i < 4; ++i)
    #pragma unroll
    for (int j = 0; j < 4; ++j) o_acc[i][j] = zf;

  const int mtile = t0 >> 6;
  const int ktf = (mtile >= 16) ? (mtile - 16) : 0;
  for (int kt = ktf; kt <= mtile; ++kt) {
    const int kb = kt * 64;
    // stage K tile (64 x 256) then V^T tile (256 x 64), reg-staged
    {
      const u16* kp = kc + (size_t)(kb + (tid >> 5)) * (NKV * HD) + kk * HD + (tid & 31) * 8;
      u16* kd = Ks + (tid >> 5) * 256 + (tid & 31) * 8;
      bf16x8 t8[8];
      #pragma unroll
      for (int is = 0; is < 8; ++is) t8[is] = *(const bf16x8*)(kp + (size_t)is * 8 * (NKV * HD));
      #pragma unroll
      for (int is = 0; is < 8; ++is) *(bf16x8*)(kd + is * 8 * 256) = t8[is];
      const u16* vp = vt + (size_t)kk * HD * T_TOK + (size_t)(tid >> 3) * T_TOK + kb + (tid & 7) * 8;
      u16* vd = Vts + (tid >> 3) * 64 + (tid & 7) * 8;
      #pragma unroll
      for (int is = 0; is < 8; ++is) t8[is] = *(const bf16x8*)(vp + (size_t)(is * 32) * T_TOK);
      #pragma unroll
      for (int is = 0; is < 8; ++is) *(bf16x8*)(vd + is * 32 * 64) = t8[is];
    }
    __syncthreads();

    // S = Q K^T : wave covers cols [wave*16, wave*16+16), all 64 rows
    f32x4 sf[4];
    #pragma unroll
    for (int i = 0; i < 4; ++i) sf[i] = zf;
    #pragma unroll
    for (int ks = 0; ks < 8; ++ks) {
      bf16x8 kfrag = *(const bf16x8*)&Ks[(wave * 16 + lc) * 256 + ks * 32 + lg * 8];
      #pragma unroll
      for (int i = 0; i < 4; ++i) {
        bf16x8 qa = *(const bf16x8*)&Qs[(i * 16 + lc) * 256 + ks * 32 + lg * 8];
        sf[i] = __builtin_amdgcn_mfma_f32_16x16x32_bf16(qa, kfrag, sf[i], 0, 0, 0);
      }
    }

    // mask (skip for fully-interior tiles)
    const int gcol = kb + wave * 16 + lc;
    const bool interior = (kb >= t0 - 960) && (kb <= t0 - 64);
    if (!interior) {
      #pragma unroll
      for (int i = 0; i < 4; ++i)
        #pragma unroll
        for (int r = 0; r < 4; ++r) {
          const int grow = t0 + i * 16 + lg * 4 + r;
          if ((unsigned)(grow - gcol) >= WIN) sf[i][r] = -1e30f;
        }
    }

    // per-row max of this wave's 16-col strip
    #pragma unroll
    for (int i = 0; i < 4; ++i) {
      float v0 = sf[i][0], v1 = sf[i][1], v2 = sf[i][2], v3 = sf[i][3];
      #pragma unroll
      for (int off = 1; off < 16; off <<= 1) {
        v0 = fmaxf(v0, __shfl_xor(v0, off));
        v1 = fmaxf(v1, __shfl_xor(v1, off));
        v2 = fmaxf(v2, __shfl_xor(v2, off));
        v3 = fmaxf(v3, __shfl_xor(v3, off));
      }
      if (lc == 0) {
        const int rb = i * 16 + lg * 4;
        m_part[wave][rb + 0] = v0;
        m_part[wave][rb + 1] = v1;
        m_part[wave][rb + 2] = v2;
        m_part[wave][rb + 3] = v3;
      }
    }
    __syncthreads();
    if (tid < 64) {
      const float tm = fmaxf(fmaxf(m_part[0][tid], m_part[1][tid]),
                             fmaxf(m_part[2][tid], m_part[3][tid]));
      const float mo = m_arr[tid];
      const float mn = fmaxf(mo, tm);
      m_arr[tid] = mn;
      a_arr[tid] = __expf(mo - mn);
    }
    __syncthreads();

    // P = exp(S - m); write bf16 to LDS; per-row partial sums; rescale O
    #pragma unroll
    for (int i = 0; i < 4; ++i) {
      const int rb = i * 16 + lg * 4;
      float p0 = __expf(sf[i][0] - m_arr[rb + 0]);
      float p1 = __expf(sf[i][1] - m_arr[rb + 1]);
      float p2 = __expf(sf[i][2] - m_arr[rb + 2]);
      float p3 = __expf(sf[i][3] - m_arr[rb + 3]);
      Ps[(rb + 0) * 64 + wave * 16 + lc] = f2bf(p0);
      Ps[(rb + 1) * 64 + wave * 16 + lc] = f2bf(p1);
      Ps[(rb + 2) * 64 + wave * 16 + lc] = f2bf(p2);
      Ps[(rb + 3) * 64 + wave * 16 + lc] = f2bf(p3);
      float su0 = p0, su1 = p1, su2 = p2, su3 = p3;
      #pragma unroll
      for (int off = 1; off < 16; off <<= 1) {
        su0 += __shfl_xor(su0, off);
        su1 += __shfl_xor(su1, off);
        su2 += __shfl_xor(su2, off);
        su3 += __shfl_xor(su3, off);
      }
      if (lc == 0) {
        s_part[wave][rb + 0] = su0;
        s_part[wave][rb + 1] = su1;
        s_part[wave][rb + 2] = su2;
        s_part[wave][rb + 3] = su3;
      }
    }
    #pragma unroll
    for (int i = 0; i < 4; ++i) {
      const int rb = i * 16 + lg * 4;
      const float a0 = a_arr[rb + 0], a1 = a_arr[rb + 1], a2 = a_arr[rb + 2], a3 = a_arr[rb + 3];
      #pragma unroll
      for (int j = 0; j < 4; ++j) {
        o_acc[i][j][0] *= a0;
        o_acc[i][j][1] *= a1;
        o_acc[i][j][2] *= a2;
        o_acc[i][j][3] *= a3;
      }
    }
    __syncthreads();
    if (tid < 64)
      l_arr[tid] = l_arr[tid] * a_arr[tid]
                 + (s_part[0][tid] + s_part[1][tid] + s_part[2][tid] + s_part[3][tid]);

    // O += P * V : wave covers output cols h in [wave*64, wave*64+64)
    #pragma unroll
    for (int ks = 0; ks < 2; ++ks) {
      bf16x8 pa[4], vb4[4];
      #pragma unroll
      for (int i = 0; i < 4; ++i)
        pa[i] = *(const bf16x8*)&Ps[(i * 16 + lc) * 64 + ks * 32 + lg * 8];
      #pragma unroll
      for (int j = 0; j < 4; ++j)
        vb4[j] = *(const bf16x8*)&Vts[(wave * 64 + j * 16 + lc) * 64 + ks * 32 + lg * 8];
      #pragma unroll
      for (int i = 0; i < 4; ++i)
        #pragma unroll
        for (int j = 0; j < 4; ++j)
          o_acc[i][j] = __builtin_amdgcn_mfma_f32_16x16x32_bf16(pa[i], vb4[j], o_acc[i][j], 0, 0, 0);
    }
    __syncthreads();
  }

  // epilogue: O / l -> attn buffer (T x 2048 bf16), col base n*256
  #pragma unroll
  for (int i = 0; i < 4; ++i) {
    const int rb = i * 16 + lg * 4;
    const float li0 = 1.f / l_arr[rb + 0];
    const float li1 = 1.f / l_arr[rb + 1];
    const float li2 = 1.f / l_arr[rb + 2];
    const float li3 = 1.f / l_arr[rb + 3];
    #pragma unroll
    for (int j = 0; j < 4; ++j) {
      const int colb = n * 256 + wave * 64 + j * 16 + lc;
      ob[(size_t)(t0 + rb + 0) * 2048 + colb] = f2bf(o_acc[i][j][0] * li0);
      ob[(size_t)(t0 + rb + 1) * 2048 + colb] = f2bf(o_acc[i][j][1] * li1);
      ob[(size_t)(t0 + rb + 2) * 2048 + colb] = f2bf(o_acc[i][j][2] * li2);
      ob[(size_t)(t0 + rb + 3) * 2048 + colb] = f2bf(o_acc[i][j][3] * li3);
    }
  }
}

// ---------------------------------------------------------------------------
extern "C" void kernel_launch(void* const* d_in, const int* in_sizes, int n_in,
                              void* d_out, int out_size, void* d_ws, size_t ws_size,
                              hipStream_t stream)
{
  (void)in_sizes; (void)n_in; (void)out_size; (void)ws_size;
  const float* x   = (const float*)d_in[0];
  const float* wq  = (const float*)d_in[1];
  const float* wk  = (const float*)d_in[2];
  const float* wv  = (const float*)d_in[3];
  const float* wo  = (const float*)d_in[4];
  const float* qnw = (const float*)d_in[5];
  const float* knw = (const float*)d_in[6];
  const int*   pos = (const int*)d_in[7];
  float* out = (float*)d_out;  // f32! [2*T*NKV*HD kv cache][T*DM o]

  // workspace layout (peak 86 MB), lifetime-aliased
  char* ws = (char*)d_ws;
  u16* woT   = (u16*)(ws);                    // 2560x2048 bf16 (10.5 MB), live to end
  u16* xb    = (u16*)(ws + 10485760);         // T x DM bf16 (21.0 MB)
  u16* wqkvT = (u16*)(ws + 31457280);         // 4096 x DM bf16 (21.0 MB)
  u16* qkv   = (u16*)(ws + 52428800);         // T x 4096 bf16 (33.6 MB)
  u16* q_b   = xb;                            // alias: xb dead after gemm1 (16.8 MB)
  u16* kb    = wqkvT;                         // alias: wqkvT dead after gemm1 (8.4 MB)
  u16* vb    = (u16*)(ws + 31457280 + 8388608); // (8.4 MB, still inside wqkvT)
  u16* vtb   = qkv;                           // alias: qkv dead after fuse (8.4 MB)
  u16* attn  = (u16*)(ws + 52428800 + 8388608); // (16.8 MB, inside qkv region)

  convert_f32_bf16<<<2048, 256, 0, stream>>>(x, xb, T_TOK * DM);
  transpose_f32_bf16<<<dim3(32, 40), 256, 0, stream>>>(wq, wqkvT, DM, 2048);
  transpose_f32_bf16<<<dim3(16, 40), 256, 0, stream>>>(wk, wqkvT + 2048 * DM, DM, 1024);
  transpose_f32_bf16<<<dim3(16, 40), 256, 0, stream>>>(wv, wqkvT + 3072 * DM, DM, 1024);
  transpose_f32_bf16<<<dim3(40, 32), 256, 0, stream>>>(wo, woT, 2048, DM);

  // QKV projection: (T x DM) * (DM x 4096) -> T x 4096 bf16
  gemm_bf16<<<dim3(32, 32), 256, 0, stream>>>(xb, wqkvT, qkv, DM, DM, DM, 4096);

  // RMSNorm + scale + RoPE; k/v f32 into kv cache (d_out) + bf16 copies
  fuse_norm_rope<<<T_TOK, 256, 0, stream>>>(qkv, qnw, knw, pos, q_b, kb, vb, out);

  // V^T per head for PV MFMA B-operand
  transpose_v<<<dim3(4, 64, 4), 256, 0, stream>>>(vb, vtb);

  // flash attention -> attn (T x 2048 bf16)
  attn_kernel<<<dim3(64, 8), 256, 0, stream>>>(q_b, kb, vtb, attn);

  // output projection: (T x 2048) * (2048 x DM) -> o (f32) in d_out
  gemm_bf16_f32out<<<dim3(20, 32), 256, 0, stream>>>(attn, woT, out + 2 * (size_t)T_TOK * NKV * HD,
                                                     2048, 2048, 2048, DM);
}

// Round 6
// 317.035 us; speedup vs baseline: 1.4495x; 1.4495x over previous
//
#include <hip/hip_runtime.h>
#include <stdint.h>

// Problem constants (Gemma3 attention block)
#define T_TOK 4096
#define DM    2560
#define NQ    8
#define NKV   4
#define HD    256
#define WIN   1024

using bf16x8 = __attribute__((ext_vector_type(8))) short;
using f32x4  = __attribute__((ext_vector_type(4))) float;
typedef unsigned short u16;

__device__ __forceinline__ u16 f2bf(float x) {
  union { float f; uint32_t u; } v; v.f = x;
  uint32_t u = v.u;
  return (u16)((u + 0x7fffu + ((u >> 16) & 1u)) >> 16);  // RNE
}
__device__ __forceinline__ float bf2f(u16 b) {
  union { uint32_t u; float f; } v; v.u = ((uint32_t)b) << 16;
  return v.f;
}

// async global->LDS, 16B per lane. LDS dest is wave-uniform base; HW adds lane*16.
__device__ __forceinline__ void async_cp16(const void* g, void* lds) {
  __builtin_amdgcn_global_load_lds(
      (const __attribute__((address_space(1))) uint32_t*)(uintptr_t)g,
      (__attribute__((address_space(3))) uint32_t*)(uint32_t)(uintptr_t)lds,
      16, 0, 0);
}

// ---------------------------------------------------------------------------
// f32 -> bf16 elementwise convert (vectorized float4 loads)
__global__ __launch_bounds__(256) void convert_f32_bf16(
    const float* __restrict__ in, u16* __restrict__ out, int n)
{
  for (int i = (blockIdx.x * 256 + threadIdx.x) * 4; i < n; i += gridDim.x * 256 * 4) {
    float4 v = *(const float4*)(in + i);
    ushort4 o;
    o.x = f2bf(v.x); o.y = f2bf(v.y); o.z = f2bf(v.z); o.w = f2bf(v.w);
    *(ushort4*)(out + i) = o;
  }
}

// ---------------------------------------------------------------------------
// Tiled transpose + convert: in f32 (R x C) row-major -> out bf16 (C x R)
__global__ __launch_bounds__(256) void transpose_f32_bf16(
    const float* __restrict__ in, u16* __restrict__ out, int R, int C)
{
  __shared__ u16 tile[64][65];
  const int r0 = blockIdx.y * 64, c0 = blockIdx.x * 64;
  const int tr = threadIdx.x >> 6, tc = threadIdx.x & 63;
  #pragma unroll
  for (int i = 0; i < 16; ++i) {
    int r = tr + i * 4;
    tile[r][tc] = f2bf(in[(size_t)(r0 + r) * C + c0 + tc]);
  }
  __syncthreads();
  #pragma unroll
  for (int i = 0; i < 16; ++i) {
    int c = tr + i * 4;
    out[(size_t)(c0 + c) * R + r0 + tc] = tile[tc][c];
  }
}

// ---------------------------------------------------------------------------
// bf16 GEMM: C(MxN) = A(MxK,row-major,lda) * B^T where B is (N x K,row-major,ldb).
// 128x128 tile, BK=64, 4 waves (2x2), global_load_lds staging, 16x16x32 MFMA.
// bf16 C store.
__global__ __launch_bounds__(256, 2) void gemm_bf16(
    const u16* __restrict__ A, const u16* __restrict__ B, u16* __restrict__ C,
    int Kd, int lda, int ldb, int ldc)
{
  __shared__ u16 As[128 * 64];
  __shared__ u16 Bs[128 * 64];
  const int tid = threadIdx.x;
  const int wave = tid >> 6, lane = tid & 63;
  const int lg = lane >> 4, lc = lane & 15;
  const int wr = wave >> 1, wc = wave & 1;
  const int m0 = blockIdx.y * 128, n0 = blockIdx.x * 128;

  const u16* Ab = A + (size_t)(m0 + (tid >> 3)) * lda + (tid & 7) * 8;
  const u16* Bb = B + (size_t)(n0 + (tid >> 3)) * ldb + (tid & 7) * 8;
  char* lAs = (char*)As + wave * 1024;
  char* lBs = (char*)Bs + wave * 1024;

  const f32x4 zf = {0.f, 0.f, 0.f, 0.f};
  f32x4 acc[4][4];
  #pragma unroll
  for (int i = 0; i < 4; ++i)
    #pragma unroll
    for (int j = 0; j < 4; ++j) acc[i][j] = zf;

  for (int kt = 0; kt < Kd; kt += 64) {
    #pragma unroll
    for (int is = 0; is < 4; ++is)
      async_cp16(Ab + (size_t)(is * 32) * lda + kt, lAs + is * 4096);
    #pragma unroll
    for (int is = 0; is < 4; ++is)
      async_cp16(Bb + (size_t)(is * 32) * ldb + kt, lBs + is * 4096);
    __syncthreads();
    #pragma unroll
    for (int kk = 0; kk < 2; ++kk) {
      bf16x8 af[4], bfr[4];
      #pragma unroll
      for (int i = 0; i < 4; ++i)
        af[i] = *(const bf16x8*)&As[(wr * 64 + i * 16 + lc) * 64 + kk * 32 + lg * 8];
      #pragma unroll
      for (int j = 0; j < 4; ++j)
        bfr[j] = *(const bf16x8*)&Bs[(wc * 64 + j * 16 + lc) * 64 + kk * 32 + lg * 8];
      #pragma unroll
      for (int i = 0; i < 4; ++i)
        #pragma unroll
        for (int j = 0; j < 4; ++j)
          acc[i][j] = __builtin_amdgcn_mfma_f32_16x16x32_bf16(af[i], bfr[j], acc[i][j], 0, 0, 0);
    }
    __syncthreads();
  }

  #pragma unroll
  for (int i = 0; i < 4; ++i)
    #pragma unroll
    for (int j = 0; j < 4; ++j)
      #pragma unroll
      for (int r = 0; r < 4; ++r) {
        int row = m0 + wr * 64 + i * 16 + lg * 4 + r;
        int col = n0 + wc * 64 + j * 16 + lc;
        C[(size_t)row * ldc + col] = f2bf(acc[i][j][r]);
      }
}

// Same GEMM, f32 C store (for the final o projection into d_out).
__global__ __launch_bounds__(256, 2) void gemm_bf16_f32out(
    const u16* __restrict__ A, const u16* __restrict__ B, float* __restrict__ C,
    int Kd, int lda, int ldb, int ldc)
{
  __shared__ u16 As[128 * 64];
  __shared__ u16 Bs[128 * 64];
  const int tid = threadIdx.x;
  const int wave = tid >> 6, lane = tid & 63;
  const int lg = lane >> 4, lc = lane & 15;
  const int wr = wave >> 1, wc = wave & 1;
  const int m0 = blockIdx.y * 128, n0 = blockIdx.x * 128;

  const u16* Ab = A + (size_t)(m0 + (tid >> 3)) * lda + (tid & 7) * 8;
  const u16* Bb = B + (size_t)(n0 + (tid >> 3)) * ldb + (tid & 7) * 8;
  char* lAs = (char*)As + wave * 1024;
  char* lBs = (char*)Bs + wave * 1024;

  const f32x4 zf = {0.f, 0.f, 0.f, 0.f};
  f32x4 acc[4][4];
  #pragma unroll
  for (int i = 0; i < 4; ++i)
    #pragma unroll
    for (int j = 0; j < 4; ++j) acc[i][j] = zf;

  for (int kt = 0; kt < Kd; kt += 64) {
    #pragma unroll
    for (int is = 0; is < 4; ++is)
      async_cp16(Ab + (size_t)(is * 32) * lda + kt, lAs + is * 4096);
    #pragma unroll
    for (int is = 0; is < 4; ++is)
      async_cp16(Bb + (size_t)(is * 32) * ldb + kt, lBs + is * 4096);
    __syncthreads();
    #pragma unroll
    for (int kk = 0; kk < 2; ++kk) {
      bf16x8 af[4], bfr[4];
      #pragma unroll
      for (int i = 0; i < 4; ++i)
        af[i] = *(const bf16x8*)&As[(wr * 64 + i * 16 + lc) * 64 + kk * 32 + lg * 8];
      #pragma unroll
      for (int j = 0; j < 4; ++j)
        bfr[j] = *(const bf16x8*)&Bs[(wc * 64 + j * 16 + lc) * 64 + kk * 32 + lg * 8];
      #pragma unroll
      for (int i = 0; i < 4; ++i)
        #pragma unroll
        for (int j = 0; j < 4; ++j)
          acc[i][j] = __builtin_amdgcn_mfma_f32_16x16x32_bf16(af[i], bfr[j], acc[i][j], 0, 0, 0);
    }
    __syncthreads();
  }

  #pragma unroll
  for (int i = 0; i < 4; ++i)
    #pragma unroll
    for (int j = 0; j < 4; ++j)
      #pragma unroll
      for (int r = 0; r < 4; ++r) {
        int row = m0 + wr * 64 + i * 16 + lg * 4 + r;
        int col = n0 + wc * 64 + j * 16 + lc;
        C[(size_t)row * ldc + col] = acc[i][j][r];
      }
}

// ---------------------------------------------------------------------------
// Fused RMSNorm + query-scale + RoPE. Reads qkv (T x 4096 bf16):
// cols [0,2048) = q (n-major), [2048,3072) = k, [3072,4096) = v.
// Writes: q -> qb (bf16), k -> kvout[0] (f32) + kb (bf16),
//         v -> kvout[1] (f32) + vb (bf16).
__global__ __launch_bounds__(256) void fuse_norm_rope(
    const u16* __restrict__ qkv, const float* __restrict__ qnw, const float* __restrict__ knw,
    const int* __restrict__ pos, u16* __restrict__ qb, u16* __restrict__ kb,
    u16* __restrict__ vb, float* __restrict__ kvout)
{
  const int t = blockIdx.x;
  const int wave = threadIdx.x >> 6, lane = threadIdx.x & 63;
  const float p = (float)pos[t];
  const float kf = 0.10381025296523007f;  // log2(10000)/128
  float s0, c0, s1, c1;
  sincosf(p * exp2f(-(float)lane * kf), &s0, &c0);
  sincosf(p * exp2f(-(float)(lane + 64) * kf), &s1, &c1);
  const u16* row = qkv + (size_t)t * 4096;

  for (int pp = 0; pp < 4; ++pp) {
    const int hr = pp * 4 + wave;  // 0..7 q, 8..11 k, 12..15 v
    if (hr >= 12) {
      const int kk = hr - 12;
      const u16* src = row + 3072 + kk * 256;
      float* dstf = kvout + (size_t)T_TOK * NKV * HD + ((size_t)t * NKV + kk) * HD;
      u16*   dstb = vb + ((size_t)t * NKV + kk) * HD;
      #pragma unroll
      for (int q4 = 0; q4 < 4; ++q4) {
        const u16 s = src[lane + q4 * 64];
        dstf[lane + q4 * 64] = bf2f(s);
        dstb[lane + q4 * 64] = s;
      }
    } else {
      const bool isq = hr < 8;
      const int cb = isq ? hr * 256 : 2048 + (hr - 8) * 256;
      float v0 = bf2f(row[cb + lane]);
      float v1 = bf2f(row[cb + lane + 64]);
      float v2 = bf2f(row[cb + lane + 128]);
      float v3 = bf2f(row[cb + lane + 192]);
      float ss = v0 * v0 + v1 * v1 + v2 * v2 + v3 * v3;
      #pragma unroll
      for (int off = 1; off < 64; off <<= 1) ss += __shfl_xor(ss, off);
      float sc = rsqrtf(ss * (1.0f / 256.0f) + 1e-6f);
      if (isq) sc *= 0.0625f;  // QUERY_PRE_ATTN_SCALAR^-0.5
      const float* wn = isq ? qnw : knw;
      v0 *= sc * wn[lane];
      v1 *= sc * wn[lane + 64];
      v2 *= sc * wn[lane + 128];
      v3 *= sc * wn[lane + 192];
      const float n0 = v0 * c0 - v2 * s0;
      const float n2 = v2 * c0 + v0 * s0;
      const float n1 = v1 * c1 - v3 * s1;
      const float n3 = v3 * c1 + v1 * s1;
      if (isq) {
        u16* dst = qb + (size_t)t * 2048 + hr * 256;
        dst[lane]       = f2bf(n0);
        dst[lane + 64]  = f2bf(n1);
        dst[lane + 128] = f2bf(n2);
        dst[lane + 192] = f2bf(n3);
      } else {
        const int kk = hr - 8;
        float* dstf = kvout + ((size_t)t * NKV + kk) * HD;
        dstf[lane]       = n0;
        dstf[lane + 64]  = n1;
        dstf[lane + 128] = n2;
        dstf[lane + 192] = n3;
        u16* dstb = kb + ((size_t)t * NKV + kk) * HD;
        dstb[lane]       = f2bf(n0);
        dstb[lane + 64]  = f2bf(n1);
        dstb[lane + 128] = f2bf(n2);
        dstb[lane + 192] = f2bf(n3);
      }
    }
  }
}

// ---------------------------------------------------------------------------
// Per-head V transpose: vb (T x NKV x HD bf16) -> vt (NKV x HD x T bf16)
__global__ __launch_bounds__(256) void transpose_v(
    const u16* __restrict__ vc, u16* __restrict__ vt)
{
  __shared__ u16 tile[64][65];
  const int kk = blockIdx.z;
  const int t0 = blockIdx.y * 64, h0 = blockIdx.x * 64;
  const int tr = threadIdx.x >> 6, tc = threadIdx.x & 63;
  #pragma unroll
  for (int i = 0; i < 16; ++i) {
    int tt = tr + i * 4;
    tile[tt][tc] = vc[((size_t)(t0 + tt) * NKV + kk) * HD + h0 + tc];
  }
  __syncthreads();
  #pragma unroll
  for (int i = 0; i < 16; ++i) {
    int h = tr + i * 4;
    vt[(size_t)kk * HD * T_TOK + (size_t)(h0 + h) * T_TOK + t0 + tc] = tile[tc][h];
  }
}

// ---------------------------------------------------------------------------
// Flash attention v2: sliding window 1024, GQA.
// Waves 2x2 over the 64x64 S-tile (32 rows x 32 cols each). Q in registers.
// K/V/P LDS tiles XOR-swizzled (byte ^= (row&7)<<4) on write AND read.
// LDS ~75 KB -> 2 blocks/CU.
__global__ __launch_bounds__(256, 2) void attn_kernel(
    const u16* __restrict__ qb, const u16* __restrict__ kc,
    const u16* __restrict__ vt, u16* __restrict__ ob)
{
  __shared__ __align__(16) u16 Ks[64 * 256];   // K tile (swz); Q staging (linear) first
  __shared__ __align__(16) u16 Vts[256 * 64];  // V^T tile (swz)
  __shared__ __align__(16) u16 Ps[64 * 64];    // P tile (swz)
  __shared__ float m_part[2][64], s_part[2][64];
  __shared__ float m_arr[64], l_arr[64], a_arr[64];

  const int n = blockIdx.y;       // q head
  const int kk = n >> 1;          // kv head
  const int t0 = blockIdx.x * 64;
  const int tid = threadIdx.x;
  const int wave = tid >> 6, lane = tid & 63;
  const int lg = lane >> 4, lc = lane & 15;
  const int wr = wave >> 1, wc = wave & 1;
  const int lswz = (lc & 7) << 4;  // read-side XOR for rows ≡ lc (mod 8)

  // ---- stage Q (64x256, linear) into Ks region, then pull fragments to regs
  {
    const u16* qp = qb + (size_t)(t0 + (tid >> 5)) * 2048 + n * 256 + (tid & 31) * 8;
    u16* qd = Ks + (tid >> 5) * 256 + (tid & 31) * 8;
    bf16x8 tq[8];
    #pragma unroll
    for (int is = 0; is < 8; ++is) tq[is] = *(const bf16x8*)(qp + (size_t)is * 8 * 2048);
    #pragma unroll
    for (int is = 0; is < 8; ++is) *(bf16x8*)(qd + is * 8 * 256) = tq[is];
  }
  if (tid < 64) { m_arr[tid] = -1e30f; l_arr[tid] = 0.f; }
  __syncthreads();
  bf16x8 qf[8][2];
  #pragma unroll
  for (int ks = 0; ks < 8; ++ks)
    #pragma unroll
    for (int i = 0; i < 2; ++i)
      qf[ks][i] = *(const bf16x8*)&Ks[(wr * 32 + i * 16 + lc) * 256 + ks * 32 + lg * 8];
  __syncthreads();  // all waves done reading Q before K overwrites the buffer

  const f32x4 zf = {0.f, 0.f, 0.f, 0.f};
  f32x4 o_acc[2][8];
  #pragma unroll
  for (int i = 0; i < 2; ++i)
    #pragma unroll
    for (int j = 0; j < 8; ++j) o_acc[i][j] = zf;

  const int mtile = t0 >> 6;
  const int ktf = (mtile >= 16) ? (mtile - 16) : 0;
  for (int kt = ktf; kt <= mtile; ++kt) {
    const int kb = kt * 64;
    // ---- stage K (swz) and V^T (swz), reg-staged
    {
      bf16x8 t8[8];
      const u16* kp = kc + (size_t)(kb + (tid >> 5)) * (NKV * HD) + kk * HD + (tid & 31) * 8;
      #pragma unroll
      for (int is = 0; is < 8; ++is) t8[is] = *(const bf16x8*)(kp + (size_t)is * 8 * (NKV * HD));
      const int kswz = ((tid >> 5) & 7) << 4;
      #pragma unroll
      for (int is = 0; is < 8; ++is)
        *(bf16x8*)((char*)Ks + ((((tid >> 5) + is * 8) * 512 + (tid & 31) * 16) ^ kswz)) = t8[is];

      const u16* vp = vt + (size_t)kk * HD * T_TOK + (size_t)(tid >> 3) * T_TOK + kb + (tid & 7) * 8;
      #pragma unroll
      for (int is = 0; is < 8; ++is) t8[is] = *(const bf16x8*)(vp + (size_t)(is * 32) * T_TOK);
      const int vswz = ((tid >> 3) & 7) << 4;
      #pragma unroll
      for (int is = 0; is < 8; ++is)
        *(bf16x8*)((char*)Vts + ((((tid >> 3) + is * 32) * 128 + (tid & 7) * 16) ^ vswz)) = t8[is];
    }
    __syncthreads();

    // ---- S = Q K^T : wave (wr,wc) covers rows wr*32+32, cols wc*32+32
    f32x4 sf[2][2];
    #pragma unroll
    for (int i = 0; i < 2; ++i) { sf[i][0] = zf; sf[i][1] = zf; }
    #pragma unroll
    for (int ks = 0; ks < 8; ++ks) {
      bf16x8 kf0 = *(const bf16x8*)((char*)Ks + (((wc * 32 + lc) * 512 + ks * 64 + lg * 16) ^ lswz));
      bf16x8 kf1 = *(const bf16x8*)((char*)Ks + (((wc * 32 + 16 + lc) * 512 + ks * 64 + lg * 16) ^ lswz));
      sf[0][0] = __builtin_amdgcn_mfma_f32_16x16x32_bf16(qf[ks][0], kf0, sf[0][0], 0, 0, 0);
      sf[0][1] = __builtin_amdgcn_mfma_f32_16x16x32_bf16(qf[ks][0], kf1, sf[0][1], 0, 0, 0);
      sf[1][0] = __builtin_amdgcn_mfma_f32_16x16x32_bf16(qf[ks][1], kf0, sf[1][0], 0, 0, 0);
      sf[1][1] = __builtin_amdgcn_mfma_f32_16x16x32_bf16(qf[ks][1], kf1, sf[1][1], 0, 0, 0);
    }

    // ---- mask (skip for fully-interior tiles)
    const bool interior = (kb >= t0 - 960) && (kb <= t0 - 64);
    if (!interior) {
      #pragma unroll
      for (int i = 0; i < 2; ++i)
        #pragma unroll
        for (int jj = 0; jj < 2; ++jj) {
          const int gcol = kb + wc * 32 + jj * 16 + lc;
          #pragma unroll
          for (int r = 0; r < 4; ++r) {
            const int grow = t0 + wr * 32 + i * 16 + lg * 4 + r;
            if ((unsigned)(grow - gcol) >= WIN) sf[i][jj][r] = -1e30f;
          }
        }
    }

    // ---- per-row max of this wave's 32-col strip
    #pragma unroll
    for (int i = 0; i < 2; ++i) {
      float v0 = fmaxf(sf[i][0][0], sf[i][1][0]);
      float v1 = fmaxf(sf[i][0][1], sf[i][1][1]);
      float v2 = fmaxf(sf[i][0][2], sf[i][1][2]);
      float v3 = fmaxf(sf[i][0][3], sf[i][1][3]);
      #pragma unroll
      for (int off = 1; off < 16; off <<= 1) {
        v0 = fmaxf(v0, __shfl_xor(v0, off));
        v1 = fmaxf(v1, __shfl_xor(v1, off));
        v2 = fmaxf(v2, __shfl_xor(v2, off));
        v3 = fmaxf(v3, __shfl_xor(v3, off));
      }
      if (lc == 0) {
        const int rb = wr * 32 + i * 16 + lg * 4;
        m_part[wc][rb + 0] = v0;
        m_part[wc][rb + 1] = v1;
        m_part[wc][rb + 2] = v2;
        m_part[wc][rb + 3] = v3;
      }
    }
    __syncthreads();
    if (tid < 64) {
      const float tm = fmaxf(m_part[0][tid], m_part[1][tid]);
      const float mo = m_arr[tid];
      const float mn = fmaxf(mo, tm);
      m_arr[tid] = mn;
      a_arr[tid] = __expf(mo - mn);
    }
    __syncthreads();

    // ---- P = exp(S - m) -> Ps (swz bf16), per-row partial sums, rescale O
    #pragma unroll
    for (int i = 0; i < 2; ++i) {
      float su0 = 0.f, su1 = 0.f, su2 = 0.f, su3 = 0.f;
      #pragma unroll
      for (int r = 0; r < 4; ++r) {
        const int row = wr * 32 + i * 16 + lg * 4 + r;
        const float m = m_arr[row];
        const float p0 = __expf(sf[i][0][r] - m);
        const float p1 = __expf(sf[i][1][r] - m);
        const int rswz = (row & 7) << 4;
        *(u16*)((char*)Ps + ((row * 128 + (wc * 32 + lc) * 2) ^ rswz))      = f2bf(p0);
        *(u16*)((char*)Ps + ((row * 128 + (wc * 32 + 16 + lc) * 2) ^ rswz)) = f2bf(p1);
        const float s = p0 + p1;
        if (r == 0) su0 = s; else if (r == 1) su1 = s; else if (r == 2) su2 = s; else su3 = s;
      }
      #pragma unroll
      for (int off = 1; off < 16; off <<= 1) {
        su0 += __shfl_xor(su0, off);
        su1 += __shfl_xor(su1, off);
        su2 += __shfl_xor(su2, off);
        su3 += __shfl_xor(su3, off);
      }
      if (lc == 0) {
        const int rb = wr * 32 + i * 16 + lg * 4;
        s_part[wc][rb + 0] = su0;
        s_part[wc][rb + 1] = su1;
        s_part[wc][rb + 2] = su2;
        s_part[wc][rb + 3] = su3;
      }
    }
    #pragma unroll
    for (int i = 0; i < 2; ++i) {
      const int rb = wr * 32 + i * 16 + lg * 4;
      const float a0 = a_arr[rb + 0], a1 = a_arr[rb + 1], a2 = a_arr[rb + 2], a3 = a_arr[rb + 3];
      #pragma unroll
      for (int j = 0; j < 8; ++j) {
        o_acc[i][j][0] *= a0;
        o_acc[i][j][1] *= a1;
        o_acc[i][j][2] *= a2;
        o_acc[i][j][3] *= a3;
      }
    }
    __syncthreads();
    if (tid < 64)
      l_arr[tid] = l_arr[tid] * a_arr[tid] + (s_part[0][tid] + s_part[1][tid]);

    // ---- O += P * V : wave covers rows wr*32+32, output cols wc*128+128
    #pragma unroll
    for (int ks = 0; ks < 2; ++ks) {
      bf16x8 pa0 = *(const bf16x8*)((char*)Ps + (((wr * 32 + lc) * 128 + ks * 64 + lg * 16) ^ lswz));
      bf16x8 pa1 = *(const bf16x8*)((char*)Ps + (((wr * 32 + 16 + lc) * 128 + ks * 64 + lg * 16) ^ lswz));
      #pragma unroll
      for (int j = 0; j < 8; ++j) {
        bf16x8 vf = *(const bf16x8*)((char*)Vts + (((wc * 128 + j * 16 + lc) * 128 + ks * 64 + lg * 16) ^ lswz));
        o_acc[0][j] = __builtin_amdgcn_mfma_f32_16x16x32_bf16(pa0, vf, o_acc[0][j], 0, 0, 0);
        o_acc[1][j] = __builtin_amdgcn_mfma_f32_16x16x32_bf16(pa1, vf, o_acc[1][j], 0, 0, 0);
      }
    }
    __syncthreads();
  }

  // ---- epilogue: O / l -> attn buffer (T x 2048 bf16), col base n*256
  #pragma unroll
  for (int i = 0; i < 2; ++i) {
    const int rb = wr * 32 + i * 16 + lg * 4;
    const float li0 = 1.f / l_arr[rb + 0];
    const float li1 = 1.f / l_arr[rb + 1];
    const float li2 = 1.f / l_arr[rb + 2];
    const float li3 = 1.f / l_arr[rb + 3];
    #pragma unroll
    for (int j = 0; j < 8; ++j) {
      const int colb = n * 256 + wc * 128 + j * 16 + lc;
      ob[(size_t)(t0 + rb + 0) * 2048 + colb] = f2bf(o_acc[i][j][0] * li0);
      ob[(size_t)(t0 + rb + 1) * 2048 + colb] = f2bf(o_acc[i][j][1] * li1);
      ob[(size_t)(t0 + rb + 2) * 2048 + colb] = f2bf(o_acc[i][j][2] * li2);
      ob[(size_t)(t0 + rb + 3) * 2048 + colb] = f2bf(o_acc[i][j][3] * li3);
    }
  }
}

// ---------------------------------------------------------------------------
extern "C" void kernel_launch(void* const* d_in, const int* in_sizes, int n_in,
                              void* d_out, int out_size, void* d_ws, size_t ws_size,
                              hipStream_t stream)
{
  (void)in_sizes; (void)n_in; (void)out_size; (void)ws_size;
  const float* x   = (const float*)d_in[0];
  const float* wq  = (const float*)d_in[1];
  const float* wk  = (const float*)d_in[2];
  const float* wv  = (const float*)d_in[3];
  const float* wo  = (const float*)d_in[4];
  const float* qnw = (const float*)d_in[5];
  const float* knw = (const float*)d_in[6];
  const int*   pos = (const int*)d_in[7];
  float* out = (float*)d_out;  // f32: [2*T*NKV*HD kv cache][T*DM o]

  // workspace layout (peak 86 MB), lifetime-aliased
  char* ws = (char*)d_ws;
  u16* woT   = (u16*)(ws);                    // 2560x2048 bf16 (10.5 MB), live to end
  u16* xb    = (u16*)(ws + 10485760);         // T x DM bf16 (21.0 MB)
  u16* wqkvT = (u16*)(ws + 31457280);         // 4096 x DM bf16 (21.0 MB)
  u16* qkv   = (u16*)(ws + 52428800);         // T x 4096 bf16 (33.6 MB)
  u16* q_b   = xb;                            // alias: xb dead after gemm1 (16.8 MB)
  u16* kb    = wqkvT;                         // alias: wqkvT dead after gemm1 (8.4 MB)
  u16* vb    = (u16*)(ws + 31457280 + 8388608); // (8.4 MB, still inside wqkvT)
  u16* vtb   = qkv;                           // alias: qkv dead after fuse (8.4 MB)
  u16* attn  = (u16*)(ws + 52428800 + 8388608); // (16.8 MB, inside qkv region)

  convert_f32_bf16<<<2048, 256, 0, stream>>>(x, xb, T_TOK * DM);
  transpose_f32_bf16<<<dim3(32, 40), 256, 0, stream>>>(wq, wqkvT, DM, 2048);
  transpose_f32_bf16<<<dim3(16, 40), 256, 0, stream>>>(wk, wqkvT + 2048 * DM, DM, 1024);
  transpose_f32_bf16<<<dim3(16, 40), 256, 0, stream>>>(wv, wqkvT + 3072 * DM, DM, 1024);
  transpose_f32_bf16<<<dim3(40, 32), 256, 0, stream>>>(wo, woT, 2048, DM);

  // QKV projection: (T x DM) * (DM x 4096) -> T x 4096 bf16
  gemm_bf16<<<dim3(32, 32), 256, 0, stream>>>(xb, wqkvT, qkv, DM, DM, DM, 4096);

  // RMSNorm + scale + RoPE; k/v f32 into kv cache (d_out) + bf16 copies
  fuse_norm_rope<<<T_TOK, 256, 0, stream>>>(qkv, qnw, knw, pos, q_b, kb, vb, out);

  // V^T per head for PV MFMA B-operand
  transpose_v<<<dim3(4, 64, 4), 256, 0, stream>>>(vb, vtb);

  // flash attention -> attn (T x 2048 bf16)
  attn_kernel<<<dim3(64, 8), 256, 0, stream>>>(q_b, kb, vtb, attn);

  // output projection: (T x 2048) * (2048 x DM) -> o (f32) in d_out
  gemm_bf16_f32out<<<dim3(20, 32), 256, 0, stream>>>(attn, woT, out + 2 * (size_t)T_TOK * NKV * HD,
                                                     2048, 2048, 2048, DM);
}

// Round 7
// 286.917 us; speedup vs baseline: 1.6016x; 1.1050x over previous
//
#include <hip/hip_runtime.h>
#include <stdint.h>

// Problem constants (Gemma3 attention block)
#define T_TOK 4096
#define DM    2560
#define NQ    8
#define NKV   4
#define HD    256
#define WIN   1024

using bf16x8 = __attribute__((ext_vector_type(8))) short;
using f32x4  = __attribute__((ext_vector_type(4))) float;
typedef unsigned short u16;

__device__ __forceinline__ u16 f2bf(float x) {
  union { float f; uint32_t u; } v; v.f = x;
  uint32_t u = v.u;
  return (u16)((u + 0x7fffu + ((u >> 16) & 1u)) >> 16);  // RNE
}
__device__ __forceinline__ float bf2f(u16 b) {
  union { uint32_t u; float f; } v; v.u = ((uint32_t)b) << 16;
  return v.f;
}

// async global->LDS, 16B per lane. LDS dest is wave-uniform base; HW adds lane*16.
__device__ __forceinline__ void async_cp16(const void* g, void* lds) {
  __builtin_amdgcn_global_load_lds(
      (const __attribute__((address_space(1))) uint32_t*)(uintptr_t)g,
      (__attribute__((address_space(3))) uint32_t*)(uint32_t)(uintptr_t)lds,
      16, 0, 0);
}

// ---------------------------------------------------------------------------
// f32 -> bf16 elementwise convert (vectorized float4 loads)
__global__ __launch_bounds__(256) void convert_f32_bf16(
    const float* __restrict__ in, u16* __restrict__ out, int n)
{
  for (int i = (blockIdx.x * 256 + threadIdx.x) * 4; i < n; i += gridDim.x * 256 * 4) {
    float4 v = *(const float4*)(in + i);
    ushort4 o;
    o.x = f2bf(v.x); o.y = f2bf(v.y); o.z = f2bf(v.z); o.w = f2bf(v.w);
    *(ushort4*)(out + i) = o;
  }
}

// ---------------------------------------------------------------------------
// Tiled transpose + convert: in f32 (R x C) row-major -> out bf16 (C x R)
__global__ __launch_bounds__(256) void transpose_f32_bf16(
    const float* __restrict__ in, u16* __restrict__ out, int R, int C)
{
  __shared__ u16 tile[64][65];
  const int r0 = blockIdx.y * 64, c0 = blockIdx.x * 64;
  const int tr = threadIdx.x >> 6, tc = threadIdx.x & 63;
  #pragma unroll
  for (int i = 0; i < 16; ++i) {
    int r = tr + i * 4;
    tile[r][tc] = f2bf(in[(size_t)(r0 + r) * C + c0 + tc]);
  }
  __syncthreads();
  #pragma unroll
  for (int i = 0; i < 16; ++i) {
    int c = tr + i * 4;
    out[(size_t)(c0 + c) * R + r0 + tc] = tile[tc][c];
  }
}

// ---------------------------------------------------------------------------
// 256x256 bf16 GEMM, counted-vmcnt double-buffered pipeline.
// C(MxN) = A(MxK,row-major,lda) * B^T, B is (N x K,row-major,ldb).
// 8 waves (2Mx4N), BK=64, LDS 128 KiB (2 buf x (A 32K + B 32K)).
// T2 swizzle: linear LDS dest (global_load_lds) + pre-swizzled global source
// + swizzled ds_read: phys_byte = row*128 + (colbyte ^ ((row&7)<<4)).
// T4: raw s_barrier + s_waitcnt vmcnt(8) -- 8 loads always in flight.
template<bool F32OUT>
__global__ __launch_bounds__(512, 2) void gemm256(
    const u16* __restrict__ A, const u16* __restrict__ B, void* __restrict__ Cv,
    int Kd, int lda, int ldb, int ldc)
{
  __shared__ __align__(16) u16 lds[2][2][256 * 64];  // [buf][A|B][row*64+col] 128 KiB
  const int tid = threadIdx.x;
  const int wave = tid >> 6, lane = tid & 63;
  const int lg = lane >> 4, lc = lane & 15;
  const int wr = wave >> 2, wc = wave & 3;  // 2 x 4 wave grid
  const int m0 = blockIdx.y * 256, n0 = blockIdx.x * 256;
  const int NT = Kd >> 6;

  // staging mapping: thread t covers LDS row srow(+64*li), 16B chunk (t&7).
  // global source col pre-swizzled so that (linear write + XOR read) = identity.
  const int srow = tid >> 3;
  const int scol = ((tid & 7) * 16) ^ ((srow & 7) << 4);  // byte col within 128B row
  const u16* Ag = A + (size_t)(m0 + srow) * lda + (scol >> 1);
  const u16* Bg = B + (size_t)(n0 + srow) * ldb + (scol >> 1);
  char* ldsA0 = (char*)&lds[0][0][0];
  char* ldsB0 = (char*)&lds[0][1][0];
  char* ldsA1 = (char*)&lds[1][0][0];
  char* ldsB1 = (char*)&lds[1][1][0];

  #define STAGE256(LA, LB, KT) do {                                         \
    const int kc_ = (KT) * 64;                                              \
    _Pragma("unroll")                                                       \
    for (int li = 0; li < 4; ++li)                                          \
      async_cp16(Ag + (size_t)(li * 64) * lda + kc_, (LA) + li * 8192 + wave * 1024); \
    _Pragma("unroll")                                                       \
    for (int li = 0; li < 4; ++li)                                          \
      async_cp16(Bg + (size_t)(li * 64) * ldb + kc_, (LB) + li * 8192 + wave * 1024); \
  } while (0)

  const f32x4 zf = {0.f, 0.f, 0.f, 0.f};
  f32x4 acc[8][4];
  #pragma unroll
  for (int i = 0; i < 8; ++i)
    #pragma unroll
    for (int j = 0; j < 4; ++j) acc[i][j] = zf;

  // prologue: stage tiles 0 and 1; wait for tile 0 (8 of 16 outstanding)
  STAGE256(ldsA0, ldsB0, 0);
  STAGE256(ldsA1, ldsB1, 1);
  asm volatile("s_waitcnt vmcnt(8)" ::: "memory");
  __builtin_amdgcn_s_barrier();
  __builtin_amdgcn_sched_barrier(0);

  for (int t = 0; t < NT; ++t) {
    const int cur = t & 1;
    const u16* Ab = &lds[cur][0][0];
    const u16* Bb = &lds[cur][1][0];

    // B fragments once per tile (reused by all 4 phases)
    bf16x8 bf[4][2];
    #pragma unroll
    for (int j = 0; j < 4; ++j)
      #pragma unroll
      for (int k2 = 0; k2 < 2; ++k2) {
        const int row = wc * 64 + j * 16 + lc;
        const int cb = k2 * 64 + lg * 16;
        bf[j][k2] = *(const bf16x8*)((const char*)Bb + row * 128 + (cb ^ ((row & 7) << 4)));
      }

    // 4 phases: 2 m-frags each, 16 MFMA per phase
    #pragma unroll
    for (int p = 0; p < 4; ++p) {
      bf16x8 af[2][2];
      #pragma unroll
      for (int im = 0; im < 2; ++im)
        #pragma unroll
        for (int k2 = 0; k2 < 2; ++k2) {
          const int row = wr * 128 + (p * 2 + im) * 16 + lc;
          const int cb = k2 * 64 + lg * 16;
          af[im][k2] = *(const bf16x8*)((const char*)Ab + row * 128 + (cb ^ ((row & 7) << 4)));
        }
      __builtin_amdgcn_s_setprio(1);
      #pragma unroll
      for (int im = 0; im < 2; ++im)
        #pragma unroll
        for (int j = 0; j < 4; ++j)
          #pragma unroll
          for (int k2 = 0; k2 < 2; ++k2)
            acc[p * 2 + im][j] = __builtin_amdgcn_mfma_f32_16x16x32_bf16(
                af[im][k2], bf[j][k2], acc[p * 2 + im][j], 0, 0, 0);
      __builtin_amdgcn_s_setprio(0);
    }

    // all waves done reading buf cur -> restage it with tile t+2
    __builtin_amdgcn_s_barrier();
    __builtin_amdgcn_sched_barrier(0);
    int nk = t + 2; if (nk > NT - 1) nk = NT - 1;  // clamped restage keeps ledger uniform
    if (cur == 0) { STAGE256(ldsA0, ldsB0, nk); } else { STAGE256(ldsA1, ldsB1, nk); }
    // wait for tile t+1 (8 newest stay in flight), then sync all waves
    asm volatile("s_waitcnt vmcnt(8)" ::: "memory");
    __builtin_amdgcn_s_barrier();
    __builtin_amdgcn_sched_barrier(0);
  }
  #undef STAGE256

  // epilogue: C write
  #pragma unroll
  for (int i = 0; i < 8; ++i)
    #pragma unroll
    for (int j = 0; j < 4; ++j)
      #pragma unroll
      for (int r = 0; r < 4; ++r) {
        const int row = m0 + wr * 128 + i * 16 + lg * 4 + r;
        const int col = n0 + wc * 64 + j * 16 + lc;
        if (F32OUT) ((float*)Cv)[(size_t)row * ldc + col] = acc[i][j][r];
        else        ((u16*)Cv)[(size_t)row * ldc + col] = f2bf(acc[i][j][r]);
      }
}

// ---------------------------------------------------------------------------
// Fused RMSNorm + query-scale + RoPE. Reads qkv (T x 4096 bf16):
// cols [0,2048) = q (n-major), [2048,3072) = k, [3072,4096) = v.
// Writes: q -> qb (bf16), k -> kvout[0] (f32) + kb (bf16),
//         v -> kvout[1] (f32) + vb (bf16).
__global__ __launch_bounds__(256) void fuse_norm_rope(
    const u16* __restrict__ qkv, const float* __restrict__ qnw, const float* __restrict__ knw,
    const int* __restrict__ pos, u16* __restrict__ qb, u16* __restrict__ kb,
    u16* __restrict__ vb, float* __restrict__ kvout)
{
  const int t = blockIdx.x;
  const int wave = threadIdx.x >> 6, lane = threadIdx.x & 63;
  const float p = (float)pos[t];
  const float kf = 0.10381025296523007f;  // log2(10000)/128
  float s0, c0, s1, c1;
  sincosf(p * exp2f(-(float)lane * kf), &s0, &c0);
  sincosf(p * exp2f(-(float)(lane + 64) * kf), &s1, &c1);
  const u16* row = qkv + (size_t)t * 4096;

  for (int pp = 0; pp < 4; ++pp) {
    const int hr = pp * 4 + wave;  // 0..7 q, 8..11 k, 12..15 v
    if (hr >= 12) {
      const int kk = hr - 12;
      const u16* src = row + 3072 + kk * 256;
      float* dstf = kvout + (size_t)T_TOK * NKV * HD + ((size_t)t * NKV + kk) * HD;
      u16*   dstb = vb + ((size_t)t * NKV + kk) * HD;
      #pragma unroll
      for (int q4 = 0; q4 < 4; ++q4) {
        const u16 s = src[lane + q4 * 64];
        dstf[lane + q4 * 64] = bf2f(s);
        dstb[lane + q4 * 64] = s;
      }
    } else {
      const bool isq = hr < 8;
      const int cb = isq ? hr * 256 : 2048 + (hr - 8) * 256;
      float v0 = bf2f(row[cb + lane]);
      float v1 = bf2f(row[cb + lane + 64]);
      float v2 = bf2f(row[cb + lane + 128]);
      float v3 = bf2f(row[cb + lane + 192]);
      float ss = v0 * v0 + v1 * v1 + v2 * v2 + v3 * v3;
      #pragma unroll
      for (int off = 1; off < 64; off <<= 1) ss += __shfl_xor(ss, off);
      float sc = rsqrtf(ss * (1.0f / 256.0f) + 1e-6f);
      if (isq) sc *= 0.0625f;  // QUERY_PRE_ATTN_SCALAR^-0.5
      const float* wn = isq ? qnw : knw;
      v0 *= sc * wn[lane];
      v1 *= sc * wn[lane + 64];
      v2 *= sc * wn[lane + 128];
      v3 *= sc * wn[lane + 192];
      const float n0 = v0 * c0 - v2 * s0;
      const float n2 = v2 * c0 + v0 * s0;
      const float n1 = v1 * c1 - v3 * s1;
      const float n3 = v3 * c1 + v1 * s1;
      if (isq) {
        u16* dst = qb + (size_t)t * 2048 + hr * 256;
        dst[lane]       = f2bf(n0);
        dst[lane + 64]  = f2bf(n1);
        dst[lane + 128] = f2bf(n2);
        dst[lane + 192] = f2bf(n3);
      } else {
        const int kk = hr - 8;
        float* dstf = kvout + ((size_t)t * NKV + kk) * HD;
        dstf[lane]       = n0;
        dstf[lane + 64]  = n1;
        dstf[lane + 128] = n2;
        dstf[lane + 192] = n3;
        u16* dstb = kb + ((size_t)t * NKV + kk) * HD;
        dstb[lane]       = f2bf(n0);
        dstb[lane + 64]  = f2bf(n1);
        dstb[lane + 128] = f2bf(n2);
        dstb[lane + 192] = f2bf(n3);
      }
    }
  }
}

// ---------------------------------------------------------------------------
// Per-head V transpose: vb (T x NKV x HD bf16) -> vt (NKV x HD x T bf16)
__global__ __launch_bounds__(256) void transpose_v(
    const u16* __restrict__ vc, u16* __restrict__ vt)
{
  __shared__ u16 tile[64][65];
  const int kk = blockIdx.z;
  const int t0 = blockIdx.y * 64, h0 = blockIdx.x * 64;
  const int tr = threadIdx.x >> 6, tc = threadIdx.x & 63;
  #pragma unroll
  for (int i = 0; i < 16; ++i) {
    int tt = tr + i * 4;
    tile[tt][tc] = vc[((size_t)(t0 + tt) * NKV + kk) * HD + h0 + tc];
  }
  __syncthreads();
  #pragma unroll
  for (int i = 0; i < 16; ++i) {
    int h = tr + i * 4;
    vt[(size_t)kk * HD * T_TOK + (size_t)(h0 + h) * T_TOK + t0 + tc] = tile[tc][h];
  }
}

// ---------------------------------------------------------------------------
// Flash attention v2: sliding window 1024, GQA.
// Waves 2x2 over the 64x64 S-tile (32 rows x 32 cols each). Q in registers.
// K/V/P LDS tiles XOR-swizzled (byte ^= (row&7)<<4) on write AND read.
__global__ __launch_bounds__(256, 2) void attn_kernel(
    const u16* __restrict__ qb, const u16* __restrict__ kc,
    const u16* __restrict__ vt, u16* __restrict__ ob)
{
  __shared__ __align__(16) u16 Ks[64 * 256];   // K tile (swz); Q staging (linear) first
  __shared__ __align__(16) u16 Vts[256 * 64];  // V^T tile (swz)
  __shared__ __align__(16) u16 Ps[64 * 64];    // P tile (swz)
  __shared__ float m_part[2][64], s_part[2][64];
  __shared__ float m_arr[64], l_arr[64], a_arr[64];

  const int n = blockIdx.y;       // q head
  const int kk = n >> 1;          // kv head
  const int t0 = blockIdx.x * 64;
  const int tid = threadIdx.x;
  const int wave = tid >> 6, lane = tid & 63;
  const int lg = lane >> 4, lc = lane & 15;
  const int wr = wave >> 1, wc = wave & 1;
  const int lswz = (lc & 7) << 4;  // read-side XOR for rows ≡ lc (mod 8)

  // ---- stage Q (64x256, linear) into Ks region, then pull fragments to regs
  {
    const u16* qp = qb + (size_t)(t0 + (tid >> 5)) * 2048 + n * 256 + (tid & 31) * 8;
    u16* qd = Ks + (tid >> 5) * 256 + (tid & 31) * 8;
    bf16x8 tq[8];
    #pragma unroll
    for (int is = 0; is < 8; ++is) tq[is] = *(const bf16x8*)(qp + (size_t)is * 8 * 2048);
    #pragma unroll
    for (int is = 0; is < 8; ++is) *(bf16x8*)(qd + is * 8 * 256) = tq[is];
  }
  if (tid < 64) { m_arr[tid] = -1e30f; l_arr[tid] = 0.f; }
  __syncthreads();
  bf16x8 qf[8][2];
  #pragma unroll
  for (int ks = 0; ks < 8; ++ks)
    #pragma unroll
    for (int i = 0; i < 2; ++i)
      qf[ks][i] = *(const bf16x8*)&Ks[(wr * 32 + i * 16 + lc) * 256 + ks * 32 + lg * 8];
  __syncthreads();  // all waves done reading Q before K overwrites the buffer

  const f32x4 zf = {0.f, 0.f, 0.f, 0.f};
  f32x4 o_acc[2][8];
  #pragma unroll
  for (int i = 0; i < 2; ++i)
    #pragma unroll
    for (int j = 0; j < 8; ++j) o_acc[i][j] = zf;

  const int mtile = t0 >> 6;
  const int ktf = (mtile >= 16) ? (mtile - 16) : 0;
  for (int kt = ktf; kt <= mtile; ++kt) {
    const int kb = kt * 64;
    // ---- stage K (swz) and V^T (swz), reg-staged
    {
      bf16x8 t8[8];
      const u16* kp = kc + (size_t)(kb + (tid >> 5)) * (NKV * HD) + kk * HD + (tid & 31) * 8;
      #pragma unroll
      for (int is = 0; is < 8; ++is) t8[is] = *(const bf16x8*)(kp + (size_t)is * 8 * (NKV * HD));
      const int kswz = ((tid >> 5) & 7) << 4;
      #pragma unroll
      for (int is = 0; is < 8; ++is)
        *(bf16x8*)((char*)Ks + ((((tid >> 5) + is * 8) * 512 + (tid & 31) * 16) ^ kswz)) = t8[is];

      const u16* vp = vt + (size_t)kk * HD * T_TOK + (size_t)(tid >> 3) * T_TOK + kb + (tid & 7) * 8;
      #pragma unroll
      for (int is = 0; is < 8; ++is) t8[is] = *(const bf16x8*)(vp + (size_t)(is * 32) * T_TOK);
      const int vswz = ((tid >> 3) & 7) << 4;
      #pragma unroll
      for (int is = 0; is < 8; ++is)
        *(bf16x8*)((char*)Vts + ((((tid >> 3) + is * 32) * 128 + (tid & 7) * 16) ^ vswz)) = t8[is];
    }
    __syncthreads();

    // ---- S = Q K^T : wave (wr,wc) covers rows wr*32+32, cols wc*32+32
    f32x4 sf[2][2];
    #pragma unroll
    for (int i = 0; i < 2; ++i) { sf[i][0] = zf; sf[i][1] = zf; }
    #pragma unroll
    for (int ks = 0; ks < 8; ++ks) {
      bf16x8 kf0 = *(const bf16x8*)((char*)Ks + (((wc * 32 + lc) * 512 + ks * 64 + lg * 16) ^ lswz));
      bf16x8 kf1 = *(const bf16x8*)((char*)Ks + (((wc * 32 + 16 + lc) * 512 + ks * 64 + lg * 16) ^ lswz));
      sf[0][0] = __builtin_amdgcn_mfma_f32_16x16x32_bf16(qf[ks][0], kf0, sf[0][0], 0, 0, 0);
      sf[0][1] = __builtin_amdgcn_mfma_f32_16x16x32_bf16(qf[ks][0], kf1, sf[0][1], 0, 0, 0);
      sf[1][0] = __builtin_amdgcn_mfma_f32_16x16x32_bf16(qf[ks][1], kf0, sf[1][0], 0, 0, 0);
      sf[1][1] = __builtin_amdgcn_mfma_f32_16x16x32_bf16(qf[ks][1], kf1, sf[1][1], 0, 0, 0);
    }

    // ---- mask (skip for fully-interior tiles)
    const bool interior = (kb >= t0 - 960) && (kb <= t0 - 64);
    if (!interior) {
      #pragma unroll
      for (int i = 0; i < 2; ++i)
        #pragma unroll
        for (int jj = 0; jj < 2; ++jj) {
          const int gcol = kb + wc * 32 + jj * 16 + lc;
          #pragma unroll
          for (int r = 0; r < 4; ++r) {
            const int grow = t0 + wr * 32 + i * 16 + lg * 4 + r;
            if ((unsigned)(grow - gcol) >= WIN) sf[i][jj][r] = -1e30f;
          }
        }
    }

    // ---- per-row max of this wave's 32-col strip
    #pragma unroll
    for (int i = 0; i < 2; ++i) {
      float v0 = fmaxf(sf[i][0][0], sf[i][1][0]);
      float v1 = fmaxf(sf[i][0][1], sf[i][1][1]);
      float v2 = fmaxf(sf[i][0][2], sf[i][1][2]);
      float v3 = fmaxf(sf[i][0][3], sf[i][1][3]);
      #pragma unroll
      for (int off = 1; off < 16; off <<= 1) {
        v0 = fmaxf(v0, __shfl_xor(v0, off));
        v1 = fmaxf(v1, __shfl_xor(v1, off));
        v2 = fmaxf(v2, __shfl_xor(v2, off));
        v3 = fmaxf(v3, __shfl_xor(v3, off));
      }
      if (lc == 0) {
        const int rb = wr * 32 + i * 16 + lg * 4;
        m_part[wc][rb + 0] = v0;
        m_part[wc][rb + 1] = v1;
        m_part[wc][rb + 2] = v2;
        m_part[wc][rb + 3] = v3;
      }
    }
    __syncthreads();
    if (tid < 64) {
      const float tm = fmaxf(m_part[0][tid], m_part[1][tid]);
      const float mo = m_arr[tid];
      const float mn = fmaxf(mo, tm);
      m_arr[tid] = mn;
      a_arr[tid] = __expf(mo - mn);
    }
    __syncthreads();

    // ---- P = exp(S - m) -> Ps (swz bf16), per-row partial sums, rescale O
    #pragma unroll
    for (int i = 0; i < 2; ++i) {
      float su0 = 0.f, su1 = 0.f, su2 = 0.f, su3 = 0.f;
      #pragma unroll
      for (int r = 0; r < 4; ++r) {
        const int row = wr * 32 + i * 16 + lg * 4 + r;
        const float m = m_arr[row];
        const float p0 = __expf(sf[i][0][r] - m);
        const float p1 = __expf(sf[i][1][r] - m);
        const int rswz = (row & 7) << 4;
        *(u16*)((char*)Ps + ((row * 128 + (wc * 32 + lc) * 2) ^ rswz))      = f2bf(p0);
        *(u16*)((char*)Ps + ((row * 128 + (wc * 32 + 16 + lc) * 2) ^ rswz)) = f2bf(p1);
        const float s = p0 + p1;
        if (r == 0) su0 = s; else if (r == 1) su1 = s; else if (r == 2) su2 = s; else su3 = s;
      }
      #pragma unroll
      for (int off = 1; off < 16; off <<= 1) {
        su0 += __shfl_xor(su0, off);
        su1 += __shfl_xor(su1, off);
        su2 += __shfl_xor(su2, off);
        su3 += __shfl_xor(su3, off);
      }
      if (lc == 0) {
        const int rb = wr * 32 + i * 16 + lg * 4;
        s_part[wc][rb + 0] = su0;
        s_part[wc][rb + 1] = su1;
        s_part[wc][rb + 2] = su2;
        s_part[wc][rb + 3] = su3;
      }
    }
    #pragma unroll
    for (int i = 0; i < 2; ++i) {
      const int rb = wr * 32 + i * 16 + lg * 4;
      const float a0 = a_arr[rb + 0], a1 = a_arr[rb + 1], a2 = a_arr[rb + 2], a3 = a_arr[rb + 3];
      #pragma unroll
      for (int j = 0; j < 8; ++j) {
        o_acc[i][j][0] *= a0;
        o_acc[i][j][1] *= a1;
        o_acc[i][j][2] *= a2;
        o_acc[i][j][3] *= a3;
      }
    }
    __syncthreads();
    if (tid < 64)
      l_arr[tid] = l_arr[tid] * a_arr[tid] + (s_part[0][tid] + s_part[1][tid]);

    // ---- O += P * V : wave covers rows wr*32+32, output cols wc*128+128
    #pragma unroll
    for (int ks = 0; ks < 2; ++ks) {
      bf16x8 pa0 = *(const bf16x8*)((char*)Ps + (((wr * 32 + lc) * 128 + ks * 64 + lg * 16) ^ lswz));
      bf16x8 pa1 = *(const bf16x8*)((char*)Ps + (((wr * 32 + 16 + lc) * 128 + ks * 64 + lg * 16) ^ lswz));
      #pragma unroll
      for (int j = 0; j < 8; ++j) {
        bf16x8 vf = *(const bf16x8*)((char*)Vts + (((wc * 128 + j * 16 + lc) * 128 + ks * 64 + lg * 16) ^ lswz));
        o_acc[0][j] = __builtin_amdgcn_mfma_f32_16x16x32_bf16(pa0, vf, o_acc[0][j], 0, 0, 0);
        o_acc[1][j] = __builtin_amdgcn_mfma_f32_16x16x32_bf16(pa1, vf, o_acc[1][j], 0, 0, 0);
      }
    }
    __syncthreads();
  }

  // ---- epilogue: O / l -> attn buffer (T x 2048 bf16), col base n*256
  #pragma unroll
  for (int i = 0; i < 2; ++i) {
    const int rb = wr * 32 + i * 16 + lg * 4;
    const float li0 = 1.f / l_arr[rb + 0];
    const float li1 = 1.f / l_arr[rb + 1];
    const float li2 = 1.f / l_arr[rb + 2];
    const float li3 = 1.f / l_arr[rb + 3];
    #pragma unroll
    for (int j = 0; j < 8; ++j) {
      const int colb = n * 256 + wc * 128 + j * 16 + lc;
      ob[(size_t)(t0 + rb + 0) * 2048 + colb] = f2bf(o_acc[i][j][0] * li0);
      ob[(size_t)(t0 + rb + 1) * 2048 + colb] = f2bf(o_acc[i][j][1] * li1);
      ob[(size_t)(t0 + rb + 2) * 2048 + colb] = f2bf(o_acc[i][j][2] * li2);
      ob[(size_t)(t0 + rb + 3) * 2048 + colb] = f2bf(o_acc[i][j][3] * li3);
    }
  }
}

// ---------------------------------------------------------------------------
extern "C" void kernel_launch(void* const* d_in, const int* in_sizes, int n_in,
                              void* d_out, int out_size, void* d_ws, size_t ws_size,
                              hipStream_t stream)
{
  (void)in_sizes; (void)n_in; (void)out_size; (void)ws_size;
  const float* x   = (const float*)d_in[0];
  const float* wq  = (const float*)d_in[1];
  const float* wk  = (const float*)d_in[2];
  const float* wv  = (const float*)d_in[3];
  const float* wo  = (const float*)d_in[4];
  const float* qnw = (const float*)d_in[5];
  const float* knw = (const float*)d_in[6];
  const int*   pos = (const int*)d_in[7];
  float* out = (float*)d_out;  // f32: [2*T*NKV*HD kv cache][T*DM o]

  // workspace layout (peak 86 MB), lifetime-aliased
  char* ws = (char*)d_ws;
  u16* woT   = (u16*)(ws);                    // 2560x2048 bf16 (10.5 MB), live to end
  u16* xb    = (u16*)(ws + 10485760);         // T x DM bf16 (21.0 MB)
  u16* wqkvT = (u16*)(ws + 31457280);         // 4096 x DM bf16 (21.0 MB)
  u16* qkv   = (u16*)(ws + 52428800);         // T x 4096 bf16 (33.6 MB)
  u16* q_b   = xb;                            // alias: xb dead after gemm1 (16.8 MB)
  u16* kb    = wqkvT;                         // alias: wqkvT dead after gemm1 (8.4 MB)
  u16* vb    = (u16*)(ws + 31457280 + 8388608); // (8.4 MB, still inside wqkvT)
  u16* vtb   = qkv;                           // alias: qkv dead after fuse (8.4 MB)
  u16* attn  = (u16*)(ws + 52428800 + 8388608); // (16.8 MB, inside qkv region)

  convert_f32_bf16<<<2048, 256, 0, stream>>>(x, xb, T_TOK * DM);
  transpose_f32_bf16<<<dim3(32, 40), 256, 0, stream>>>(wq, wqkvT, DM, 2048);
  transpose_f32_bf16<<<dim3(16, 40), 256, 0, stream>>>(wk, wqkvT + 2048 * DM, DM, 1024);
  transpose_f32_bf16<<<dim3(16, 40), 256, 0, stream>>>(wv, wqkvT + 3072 * DM, DM, 1024);
  transpose_f32_bf16<<<dim3(40, 32), 256, 0, stream>>>(wo, woT, 2048, DM);

  // QKV projection: (T x DM) * (DM x 4096) -> T x 4096 bf16 (256 blocks = 1/CU)
  gemm256<false><<<dim3(16, 16), 512, 0, stream>>>(xb, wqkvT, qkv, DM, DM, DM, 4096);

  // RMSNorm + scale + RoPE; k/v f32 into kv cache (d_out) + bf16 copies
  fuse_norm_rope<<<T_TOK, 256, 0, stream>>>(qkv, qnw, knw, pos, q_b, kb, vb, out);

  // V^T per head for PV MFMA B-operand
  transpose_v<<<dim3(4, 64, 4), 256, 0, stream>>>(vb, vtb);

  // flash attention -> attn (T x 2048 bf16)
  attn_kernel<<<dim3(64, 8), 256, 0, stream>>>(q_b, kb, vtb, attn);

  // output projection: (T x 2048) * (2048 x DM) -> o (f32) in d_out
  gemm256<true><<<dim3(10, 16), 512, 0, stream>>>(attn, woT, out + 2 * (size_t)T_TOK * NKV * HD,
                                                  2048, 2048, 2048, DM);
}